// Round 2
// baseline (173.354 us; speedup 1.0000x reference)
//
#include <hip/hip_runtime.h>
#include <hip/hip_bf16.h>
#include <stdint.h>

#define NN 8192
#define FF 256

typedef unsigned short u16;
typedef __attribute__((ext_vector_type(4))) float f32x4;
typedef __attribute__((ext_vector_type(8))) short s16x8;
typedef __attribute__((ext_vector_type(8))) __bf16 bf16x8;

// round-half-up f32->bf16 (cheap; adj >= 0, bias negligible)
__device__ inline u16 bf_rhu(float f) {
  union { float f; unsigned u; } v; v.f = f;
  return (u16)((v.u + 0x8000u) >> 16);
}
// round-to-nearest-even f32->bf16
__device__ inline u16 f2bf_rne(float f) {
  union { float f; unsigned u; } v; v.f = f;
  unsigned r = v.u + 0x7FFFu + ((v.u >> 16) & 1u);
  return (u16)(r >> 16);
}

__device__ inline void gld_lds16(const void* g, void* l) {
  __builtin_amdgcn_global_load_lds(
      (const __attribute__((address_space(1))) void*)g,
      (__attribute__((address_space(3))) void*)l, 16, 0, 0);
}

// ---------------- K1: rowsum -> dis[i] = rsqrt(rowsum) ----------------
__global__ __launch_bounds__(256) void k_rowsum(const float* __restrict__ adj,
                                                float* __restrict__ dis) {
  const int row = blockIdx.x;
  const int t = threadIdx.x;
  const f32x4* p = reinterpret_cast<const f32x4*>(adj + (size_t)row * NN);
  float s = 0.f;
#pragma unroll
  for (int q = 0; q < 8; ++q) {
    f32x4 v = p[q * 256 + t];
    s += (v.x + v.y) + (v.z + v.w);
  }
#pragma unroll
  for (int o = 32; o > 0; o >>= 1) s += __shfl_down(s, o);
  __shared__ float red[4];
  if ((t & 63) == 0) red[t >> 6] = s;
  __syncthreads();
  if (t == 0) {
    float tot = (red[0] + red[1]) + (red[2] + red[3]);
    dis[row] = tot > 0.f ? 1.0f / sqrtf(tot) : 0.f;
  }
}

// ------- K2: xsT[f][j] = bf16(dis[j] * x[j][f])  (transposed, scaled) -------
__global__ __launch_bounds__(256) void k_xst(const float* __restrict__ x,
                                             const float* __restrict__ dis,
                                             u16* __restrict__ xsT) {
  __shared__ float tile[64][65];
  const int j0 = blockIdx.x * 64, f0 = blockIdx.y * 64;
  const int t = threadIdx.x;
  const int tr = t >> 4, tc = (t & 15) * 4;
#pragma unroll
  for (int q = 0; q < 4; ++q) {
    int r = q * 16 + tr;
    f32x4 v = *reinterpret_cast<const f32x4*>(x + (size_t)(j0 + r) * FF + f0 + tc);
    tile[r][tc] = v.x; tile[r][tc + 1] = v.y; tile[r][tc + 2] = v.z; tile[r][tc + 3] = v.w;
  }
  __syncthreads();
  float d[4];
#pragma unroll
  for (int e = 0; e < 4; ++e) d[e] = dis[j0 + tc + e];
#pragma unroll
  for (int q = 0; q < 4; ++q) {
    int fr = q * 16 + tr;
    ushort4 o;
    o.x = f2bf_rne(tile[tc + 0][fr] * d[0]);
    o.y = f2bf_rne(tile[tc + 1][fr] * d[1]);
    o.z = f2bf_rne(tile[tc + 2][fr] * d[2]);
    o.w = f2bf_rne(tile[tc + 3][fr] * d[3]);
    *reinterpret_cast<ushort4*>(xsT + (size_t)(f0 + fr) * NN + j0 + tc) = o;
  }
}

// ---------------- K2c: Wb = bf16(W), layout unchanged [o][f] ----------------
__global__ __launch_bounds__(256) void k_wb(const float* __restrict__ W,
                                            u16* __restrict__ Wb) {
  int idx = (blockIdx.x * 256 + threadIdx.x) * 4;
  f32x4 v = *reinterpret_cast<const f32x4*>(W + idx);
  ushort4 o;
  o.x = f2bf_rne(v.x); o.y = f2bf_rne(v.y); o.z = f2bf_rne(v.z); o.w = f2bf_rne(v.w);
  *reinterpret_cast<ushort4*>(Wb + idx) = o;
}

// -------- K3: fully fused  out = dis[i]*(adj_tile @ xsT^T) @ W^T + b --------
// tile 32x256 (full F width: adj read ONCE), grid 256 = 1 block/CU,
// 512 thr = 8 waves (2M x 4N, each 16x64). No split-K, no part buffer.
__global__ __launch_bounds__(512, 2) void k_gemm_fused(
    const float* __restrict__ adj, const u16* __restrict__ xsT,
    const float* __restrict__ dis, const u16* __restrict__ Wb,
    const float* __restrict__ bias, float* __restrict__ out) {
  __shared__ __align__(16) u16 As[2][32 * 64];    // swizzled slot = r*8 + (c8^(r&7))
  __shared__ __align__(16) u16 Bs[2][256 * 64];   // linear dest, pre-swizzled source
  __shared__ __align__(16) u16 Ht[32 * 256];      // swizzled slot = r*32 + (cg^(r&7))

  const int bm = blockIdx.x;            // 0..255
  const size_t i0 = (size_t)bm * 32;
  const int t = threadIdx.x;
  const int lane = t & 63;
  const int w = t >> 6;                 // 0..7
  const int wr = w >> 2;                // 0..1 (16 rows each)
  const int wc = w & 3;                 // 0..3 (64 cols each)

  f32x4 acc[4] = {};                    // 1 M-frag x 4 N-frags
  f32x4 areg[2];
  const int ar_ = t >> 3, ac_ = t & 7;  // A chunk coords (t<256): row, col-group

  auto loadA = [&](int kt) {
    if (t < 256) {
      const float* g = adj + (i0 + ar_) * (size_t)NN + kt * 64 + ac_ * 8;
      areg[0] = *reinterpret_cast<const f32x4*>(g);
      areg[1] = *reinterpret_cast<const f32x4*>(g + 4);
    }
  };
  auto writeA = [&](int buf) {
    if (t < 256) {
      int slot = ar_ * 8 + (ac_ ^ (ar_ & 7));
      s16x8 o;
#pragma unroll
      for (int e = 0; e < 4; ++e) o[e] = (short)bf_rhu(areg[0][e]);
#pragma unroll
      for (int e = 0; e < 4; ++e) o[4 + e] = (short)bf_rhu(areg[1][e]);
      *reinterpret_cast<s16x8*>(&As[buf][slot * 8]) = o;
    }
  };
  auto stageB = [&](int buf, int kt) {
#pragma unroll
    for (int q = 0; q < 4; ++q) {
      int s = (w * 4 + q) * 64 + lane;
      int r = s >> 3, pp = s & 7;
      int c = pp ^ (r & 7);               // inverse swizzle on global source
      const u16* g = xsT + (size_t)r * NN + kt * 64 + c * 8;
      gld_lds16(g, &Bs[buf][(w * 4 + q) * 512]);
    }
  };
  auto compute = [&](int buf) {
#pragma unroll
    for (int kk = 0; kk < 2; ++kk) {
      const int cg = kk * 4 + (lane >> 4);
      const int r = wr * 16 + (lane & 15);
      bf16x8 af = __builtin_bit_cast(bf16x8,
          *reinterpret_cast<const s16x8*>(&As[buf][(r * 8 + (cg ^ (r & 7))) * 8]));
      bf16x8 bfv[4];
#pragma unroll
      for (int ni = 0; ni < 4; ++ni) {
        int n = wc * 64 + ni * 16 + (lane & 15);
        bfv[ni] = __builtin_bit_cast(bf16x8,
            *reinterpret_cast<const s16x8*>(&Bs[buf][(n * 8 + (cg ^ (n & 7))) * 8]));
      }
#pragma unroll
      for (int ni = 0; ni < 4; ++ni)
        acc[ni] = __builtin_amdgcn_mfma_f32_16x16x32_bf16(af, bfv[ni], acc[ni], 0, 0, 0);
    }
  };

  loadA(0);
  stageB(0, 0);
  writeA(0);
  __syncthreads();
#pragma unroll 2
  for (int kt = 0; kt < 128; ++kt) {
    int buf = kt & 1;
    if (kt + 1 < 128) {
      loadA(kt + 1);
      stageB(buf ^ 1, kt + 1);
    }
    compute(buf);
    if (kt + 1 < 128) writeA(buf ^ 1);
    __syncthreads();
  }

  // ---- epilogue part 1: h = bf16(dis[i] * acc) -> Ht (swizzled LDS) ----
  const int r0 = wr * 16 + ((lane >> 4) * 4);
  float dv[4];
#pragma unroll
  for (int e = 0; e < 4; ++e) dv[e] = dis[i0 + r0 + e];
#pragma unroll
  for (int ni = 0; ni < 4; ++ni) {
    int c = wc * 64 + ni * 16 + (lane & 15);
    int cg = c >> 3, ce = c & 7;
#pragma unroll
    for (int e = 0; e < 4; ++e) {
      int r = r0 + e;
      Ht[(r * 32 + (cg ^ (r & 7))) * 8 + ce] = f2bf_rne(acc[ni][e] * dv[e]);
    }
  }
  __syncthreads();

  // ---- epilogue part 2: out_tile = Ht @ W^T + b (W-frags straight from L2) ----
  f32x4 occ[4] = {};
#pragma unroll
  for (int ks = 0; ks < 8; ++ks) {
    int cg = ks * 4 + (lane >> 4);         // global k-group 0..31
    int ar = wr * 16 + (lane & 15);
    bf16x8 af = __builtin_bit_cast(bf16x8,
        *reinterpret_cast<const s16x8*>(&Ht[(ar * 32 + (cg ^ (ar & 7))) * 8]));
#pragma unroll
    for (int ni = 0; ni < 4; ++ni) {
      int n = wc * 64 + ni * 16 + (lane & 15);
      bf16x8 bfv = __builtin_bit_cast(bf16x8,
          *reinterpret_cast<const s16x8*>(Wb + (size_t)n * FF + cg * 8));
      occ[ni] = __builtin_amdgcn_mfma_f32_16x16x32_bf16(af, bfv, occ[ni], 0, 0, 0);
    }
  }
#pragma unroll
  for (int ni = 0; ni < 4; ++ni) {
    int c = wc * 64 + ni * 16 + (lane & 15);
    float bb = bias[c];
#pragma unroll
    for (int e = 0; e < 4; ++e)
      out[(i0 + r0 + e) * FF + c] = occ[ni][e] + bb;
  }
}

extern "C" void kernel_launch(void* const* d_in, const int* in_sizes, int n_in,
                              void* d_out, int out_size, void* d_ws, size_t ws_size,
                              hipStream_t stream) {
  (void)in_sizes; (void)n_in; (void)out_size; (void)ws_size;
  const float* x   = (const float*)d_in[0];
  const float* adj = (const float*)d_in[1];
  const float* W   = (const float*)d_in[2];
  const float* b   = (const float*)d_in[3];
  float* out = (float*)d_out;
  char* ws = (char*)d_ws;

  // workspace: dis 32KB | xsT 4MB | Wb 128KB
  float* dis = (float*)ws;
  u16* xsT   = (u16*)(ws + (32u << 10));
  u16* Wb    = (u16*)(ws + (32u << 10) + (4u << 20));

  k_rowsum<<<dim3(8192), dim3(256), 0, stream>>>(adj, dis);
  k_xst<<<dim3(128, 4), dim3(256), 0, stream>>>(x, dis, xsT);
  k_wb<<<dim3(64), dim3(256), 0, stream>>>(W, Wb);
  k_gemm_fused<<<dim3(256), dim3(512), 0, stream>>>(adj, xsT, dis, Wb, b, out);
}

// Round 3
// 157.664 us; speedup vs baseline: 1.0995x; 1.0995x over previous
//
#include <hip/hip_runtime.h>
#include <hip/hip_bf16.h>
#include <stdint.h>

#define NN 8192
#define FF 256

typedef unsigned short u16;
typedef __attribute__((ext_vector_type(4))) float f32x4;
typedef __attribute__((ext_vector_type(8))) short s16x8;
typedef __attribute__((ext_vector_type(8))) __bf16 bf16x8;

// round-to-nearest-even f32->bf16
__device__ inline u16 f2bf_rne(float f) {
  union { float f; unsigned u; } v; v.f = f;
  unsigned r = v.u + 0x7FFFu + ((v.u >> 16) & 1u);
  return (u16)(r >> 16);
}

__device__ inline void gld_lds16(const void* g, void* l) {
  __builtin_amdgcn_global_load_lds(
      (const __attribute__((address_space(1))) void*)g,
      (__attribute__((address_space(3))) void*)l, 16, 0, 0);
}

// ------- K1: rowsum -> dis[i] = rsqrt(rowsum); also adjb = bf16(adj) -------
__global__ __launch_bounds__(256) void k_rowsum_cvt(const float* __restrict__ adj,
                                                    u16* __restrict__ adjb,
                                                    float* __restrict__ dis) {
  const int row = blockIdx.x;
  const int t = threadIdx.x;
  const float* p = adj + (size_t)row * NN;
  u16* pb = adjb + (size_t)row * NN;
  float s = 0.f;
#pragma unroll
  for (int q = 0; q < 8; ++q) {
    int e = (q * 256 + t) * 4;
    f32x4 v = *reinterpret_cast<const f32x4*>(p + e);
    ushort4 o;
    o.x = f2bf_rne(v.x); o.y = f2bf_rne(v.y);
    o.z = f2bf_rne(v.z); o.w = f2bf_rne(v.w);
    *reinterpret_cast<ushort4*>(pb + e) = o;
    s += (v.x + v.y) + (v.z + v.w);
  }
#pragma unroll
  for (int o = 32; o > 0; o >>= 1) s += __shfl_down(s, o);
  __shared__ float red[4];
  if ((t & 63) == 0) red[t >> 6] = s;
  __syncthreads();
  if (t == 0) {
    float tot = (red[0] + red[1]) + (red[2] + red[3]);
    dis[row] = tot > 0.f ? 1.0f / sqrtf(tot) : 0.f;
  }
}

// ------- K2: xsT[f][j] = bf16(dis[j] * x[j][f])  (transposed, scaled) -------
__global__ __launch_bounds__(256) void k_xst(const float* __restrict__ x,
                                             const float* __restrict__ dis,
                                             u16* __restrict__ xsT) {
  __shared__ float tile[64][65];
  const int j0 = blockIdx.x * 64, f0 = blockIdx.y * 64;
  const int t = threadIdx.x;
  const int tr = t >> 4, tc = (t & 15) * 4;
#pragma unroll
  for (int q = 0; q < 4; ++q) {
    int r = q * 16 + tr;
    f32x4 v = *reinterpret_cast<const f32x4*>(x + (size_t)(j0 + r) * FF + f0 + tc);
    tile[r][tc] = v.x; tile[r][tc + 1] = v.y; tile[r][tc + 2] = v.z; tile[r][tc + 3] = v.w;
  }
  __syncthreads();
  float d[4];
#pragma unroll
  for (int e = 0; e < 4; ++e) d[e] = dis[j0 + tc + e];
#pragma unroll
  for (int q = 0; q < 4; ++q) {
    int fr = q * 16 + tr;
    ushort4 o;
    o.x = f2bf_rne(tile[tc + 0][fr] * d[0]);
    o.y = f2bf_rne(tile[tc + 1][fr] * d[1]);
    o.z = f2bf_rne(tile[tc + 2][fr] * d[2]);
    o.w = f2bf_rne(tile[tc + 3][fr] * d[3]);
    *reinterpret_cast<ushort4*>(xsT + (size_t)(f0 + fr) * NN + j0 + tc) = o;
  }
}

// ---------------- K2c: Wb = bf16(W), layout unchanged [o][f] ----------------
__global__ __launch_bounds__(256) void k_wb(const float* __restrict__ W,
                                            u16* __restrict__ Wb) {
  int idx = (blockIdx.x * 256 + threadIdx.x) * 4;
  f32x4 v = *reinterpret_cast<const f32x4*>(W + idx);
  ushort4 o;
  o.x = f2bf_rne(v.x); o.y = f2bf_rne(v.y); o.z = f2bf_rne(v.z); o.w = f2bf_rne(v.w);
  *reinterpret_cast<ushort4*>(Wb + idx) = o;
}

// -------- K3: split-K GEMM  part[kc] += adjb_tile @ xsT^T --------
// BM=128 BN=256 BK=64, kc=4, grid 256 (1/CU), 512 thr (8 waves, 64x64 each).
// 3-deep LDS pipeline, counted vmcnt(6), raw s_barrier (1 per K-step).
// XCD decode: xcd=wg&7 -> kc=xcd>>1 so each XCD's 32 blocks share one 1MB
// B-slice (L2-resident) -- R2's B-traffic failure mode fixed.
__global__ __launch_bounds__(512, 2) void k_gemm1(const u16* __restrict__ adjb,
                                                  const u16* __restrict__ xsT,
                                                  float* __restrict__ part) {
  __shared__ __align__(16) u16 As[3][128 * 64];   // 48 KB
  __shared__ __align__(16) u16 Bs[3][256 * 64];   // 96 KB
  const int wg = blockIdx.x;
  const int xcd = wg & 7, slot = wg >> 3;
  const int kc = xcd >> 1;                        // 2 XCDs per kc-slice
  const int bm = (xcd & 1) * 32 + slot;           // 0..63
  const size_t i0 = (size_t)bm * 128;
  const int k0 = kc * 2048;
  const int t = threadIdx.x;
  const int lane = t & 63;
  const int w = t >> 6;                 // 0..7
  const int wr = w >> 2;                // 0..1 (64 rows each)
  const int wc = w & 3;                 // 0..3 (64 cols each)

  f32x4 acc[4][4] = {};

  auto STAGE = [&](int buf, int kt) {
    const int kbase = k0 + kt * 64;
    // A: 128x64 bf16, 2 gld_lds per wave; linear dest, inverse-swz source
#pragma unroll
    for (int q = 0; q < 2; ++q) {
      int s = (w * 2 + q) * 64 + lane;
      int r = s >> 3, cg = (s & 7) ^ (r & 7);
      gld_lds16(adjb + (i0 + r) * (size_t)NN + kbase + cg * 8,
                &As[buf][(w * 2 + q) * 512]);
    }
    // B: 256x64 bf16, 4 gld_lds per wave
#pragma unroll
    for (int q = 0; q < 4; ++q) {
      int s = (w * 4 + q) * 64 + lane;
      int r = s >> 3, cg = (s & 7) ^ (r & 7);
      gld_lds16(xsT + (size_t)r * NN + kbase + cg * 8,
                &Bs[buf][(w * 4 + q) * 512]);
    }
  };
  auto COMPUTE = [&](int buf) {
#pragma unroll
    for (int kk = 0; kk < 2; ++kk) {
      const int cg = kk * 4 + (lane >> 4);
      bf16x8 af[4], bfv[4];
#pragma unroll
      for (int mi = 0; mi < 4; ++mi) {
        int r = wr * 64 + mi * 16 + (lane & 15);
        af[mi] = __builtin_bit_cast(bf16x8,
            *reinterpret_cast<const s16x8*>(&As[buf][(r * 8 + (cg ^ (r & 7))) * 8]));
      }
#pragma unroll
      for (int ni = 0; ni < 4; ++ni) {
        int n = wc * 64 + ni * 16 + (lane & 15);
        bfv[ni] = __builtin_bit_cast(bf16x8,
            *reinterpret_cast<const s16x8*>(&Bs[buf][(n * 8 + (cg ^ (n & 7))) * 8]));
      }
#pragma unroll
      for (int mi = 0; mi < 4; ++mi)
#pragma unroll
        for (int ni = 0; ni < 4; ++ni)
          acc[mi][ni] = __builtin_amdgcn_mfma_f32_16x16x32_bf16(af[mi], bfv[ni], acc[mi][ni], 0, 0, 0);
    }
  };

  STAGE(0, 0);
  STAGE(1, 1);
  int b0 = 0, b1 = 1, b2 = 2;
  for (int kt = 0; kt < 30; ++kt) {
    // own 12 outstanding (t,t+1); wait to 6 => t's staged loads complete
    asm volatile("s_waitcnt vmcnt(6)" ::: "memory");
    __builtin_amdgcn_s_barrier();
    asm volatile("" ::: "memory");
    STAGE(b2, kt + 2);
    COMPUTE(b0);
    int tmp = b0; b0 = b1; b1 = b2; b2 = tmp;
  }
  for (int kt = 30; kt < 32; ++kt) {
    asm volatile("s_waitcnt vmcnt(0)" ::: "memory");
    __builtin_amdgcn_s_barrier();
    asm volatile("" ::: "memory");
    COMPUTE(b0);
    int tmp = b0; b0 = b1; b1 = b2; b2 = tmp;
  }

  float* pout = part + (size_t)kc * ((size_t)NN * FF);
#pragma unroll
  for (int mi = 0; mi < 4; ++mi) {
    int rbase = wr * 64 + mi * 16 + ((lane >> 4) * 4);
#pragma unroll
    for (int ni = 0; ni < 4; ++ni) {
      int cc = wc * 64 + ni * 16 + (lane & 15);
#pragma unroll
      for (int e = 0; e < 4; ++e)
        pout[(i0 + rbase + e) * FF + cc] = acc[mi][ni][e];
    }
  }
}

// -------- K4: out = (dis[i] * sum_kc part) @ W^T + b  (fused, tile 32x256) --------
__global__ __launch_bounds__(256) void k_out(const float* __restrict__ part,
                                             const float* __restrict__ dis,
                                             const u16* __restrict__ Wb,
                                             const float* __restrict__ bias,
                                             float* __restrict__ out) {
  __shared__ __align__(16) u16 Hs[32 * 256];   // 16 KB, slot = r*32 + (c8^(r&7))
  const int bm = blockIdx.x;
  const size_t i0 = (size_t)bm * 32;
  const int t = threadIdx.x, lane = t & 63, w = t >> 6;   // 4 waves
  const int wr = w >> 1, wc = w & 1;
  const size_t SL = (size_t)NN * FF;

  // stage h-tile: sum 4 part slices, scale by dis[i], cvt bf16, swizzled LDS
#pragma unroll
  for (int s8 = 0; s8 < 8; ++s8) {
    int e = s8 * 1024 + t * 4;
    int r = e >> 8, c = e & 255;
    const float* p = part + i0 * FF + e;
    f32x4 v = *reinterpret_cast<const f32x4*>(p)
            + *reinterpret_cast<const f32x4*>(p + SL)
            + *reinterpret_cast<const f32x4*>(p + 2 * SL)
            + *reinterpret_cast<const f32x4*>(p + 3 * SL);
    float d = dis[i0 + r];
    ushort4 o;
    o.x = f2bf_rne(v.x * d); o.y = f2bf_rne(v.y * d);
    o.z = f2bf_rne(v.z * d); o.w = f2bf_rne(v.w * d);
    int c8 = c >> 3;
    *reinterpret_cast<ushort4*>(&Hs[(r * 32 + (c8 ^ (r & 7))) * 8 + (c & 7)]) = o;
  }
  __syncthreads();

  f32x4 occ[8] = {};
#pragma unroll
  for (int ks = 0; ks < 8; ++ks) {
    int cg = ks * 4 + (lane >> 4);
    int ar = wr * 16 + (lane & 15);
    bf16x8 af = __builtin_bit_cast(bf16x8,
        *reinterpret_cast<const s16x8*>(&Hs[(ar * 32 + (cg ^ (ar & 7))) * 8]));
#pragma unroll
    for (int ni = 0; ni < 8; ++ni) {
      int n = wc * 128 + ni * 16 + (lane & 15);
      bf16x8 bfv = __builtin_bit_cast(bf16x8,
          *reinterpret_cast<const s16x8*>(Wb + (size_t)n * FF + cg * 8));
      occ[ni] = __builtin_amdgcn_mfma_f32_16x16x32_bf16(af, bfv, occ[ni], 0, 0, 0);
    }
  }

  int r0 = wr * 16 + (lane >> 4) * 4;
#pragma unroll
  for (int ni = 0; ni < 8; ++ni) {
    int c = wc * 128 + ni * 16 + (lane & 15);
    float bb = bias[c];
#pragma unroll
    for (int e = 0; e < 4; ++e)
      out[(i0 + r0 + e) * FF + c] = occ[ni][e] + bb;
  }
}

extern "C" void kernel_launch(void* const* d_in, const int* in_sizes, int n_in,
                              void* d_out, int out_size, void* d_ws, size_t ws_size,
                              hipStream_t stream) {
  (void)in_sizes; (void)n_in; (void)out_size; (void)ws_size;
  const float* x   = (const float*)d_in[0];
  const float* adj = (const float*)d_in[1];
  const float* W   = (const float*)d_in[2];
  const float* b   = (const float*)d_in[3];
  float* out = (float*)d_out;
  char* ws = (char*)d_ws;

  // ws: dis 32KB @0 | xsT 4MB @64KB | Wb 128KB @(64KB+4MB) | part 32MB @8MB | adjb 128MB @48MB
  float* dis  = (float*)ws;
  u16*   xsT  = (u16*)(ws + (64u << 10));
  u16*   Wb   = (u16*)(ws + (64u << 10) + (4u << 20));
  float* part = (float*)(ws + (8u << 20));
  u16*   adjb = (u16*)(ws + (48u << 20));

  k_rowsum_cvt<<<dim3(8192), dim3(256), 0, stream>>>(adj, adjb, dis);
  k_xst<<<dim3(128, 4), dim3(256), 0, stream>>>(x, dis, xsT);
  k_wb<<<dim3(64), dim3(256), 0, stream>>>(W, Wb);
  k_gemm1<<<dim3(256), dim3(512), 0, stream>>>(adjb, xsT, part);
  k_out<<<dim3(256), dim3(256), 0, stream>>>(part, dis, Wb, b, out);
}

// Round 4
// 154.407 us; speedup vs baseline: 1.1227x; 1.0211x over previous
//
#include <hip/hip_runtime.h>
#include <hip/hip_bf16.h>
#include <stdint.h>

#define NN 8192
#define FF 256

typedef unsigned short u16;
typedef __attribute__((ext_vector_type(4))) float f32x4;
typedef __attribute__((ext_vector_type(4))) unsigned int u32x4;
typedef __attribute__((ext_vector_type(8))) short s16x8;
typedef __attribute__((ext_vector_type(8))) __bf16 bf16x8;

// round-to-nearest-even f32->bf16
__device__ inline u16 f2bf_rne(float f) {
  union { float f; unsigned u; } v; v.f = f;
  unsigned r = v.u + 0x7FFFu + ((v.u >> 16) & 1u);
  return (u16)(r >> 16);
}

__device__ inline void gld_lds16(const void* g, void* l) {
  __builtin_amdgcn_global_load_lds(
      (const __attribute__((address_space(1))) void*)g,
      (__attribute__((address_space(3))) void*)l, 16, 0, 0);
}

// ------- K1: rowsum -> dis[i] = rsqrt(rowsum); also adjb = bf16(adj) -------
__global__ __launch_bounds__(256) void k_rowsum_cvt(const float* __restrict__ adj,
                                                    u16* __restrict__ adjb,
                                                    float* __restrict__ dis) {
  const int row = blockIdx.x;
  const int t = threadIdx.x;
  const float* p = adj + (size_t)row * NN;
  u16* pb = adjb + (size_t)row * NN;
  float s = 0.f;
#pragma unroll
  for (int q = 0; q < 8; ++q) {
    int e = (q * 256 + t) * 4;
    f32x4 v = *reinterpret_cast<const f32x4*>(p + e);
    ushort4 o;
    o.x = f2bf_rne(v.x); o.y = f2bf_rne(v.y);
    o.z = f2bf_rne(v.z); o.w = f2bf_rne(v.w);
    *reinterpret_cast<ushort4*>(pb + e) = o;
    s += (v.x + v.y) + (v.z + v.w);
  }
#pragma unroll
  for (int o = 32; o > 0; o >>= 1) s += __shfl_down(s, o);
  __shared__ float red[4];
  if ((t & 63) == 0) red[t >> 6] = s;
  __syncthreads();
  if (t == 0) {
    float tot = (red[0] + red[1]) + (red[2] + red[3]);
    dis[row] = tot > 0.f ? 1.0f / sqrtf(tot) : 0.f;
  }
}

// ---------------- K2: Wb = bf16(W), layout unchanged [o][f] ----------------
__global__ __launch_bounds__(256) void k_wb(const float* __restrict__ W,
                                            u16* __restrict__ Wb) {
  int idx = (blockIdx.x * 256 + threadIdx.x) * 4;
  f32x4 v = *reinterpret_cast<const f32x4*>(W + idx);
  ushort4 o;
  o.x = f2bf_rne(v.x); o.y = f2bf_rne(v.y); o.z = f2bf_rne(v.z); o.w = f2bf_rne(v.w);
  *reinterpret_cast<ushort4*>(Wb + idx) = o;
}

// ------- K3: xwT[fo][j] = bf16( dis[j] * (x @ W^T)[j][fo] )  (transposed) -------
// block: 32 j-rows x 256 fo, 4 waves; A = dis*x staged bf16 in LDS (swizzled),
// B = Wb rows straight from L2; LDS transpose for coalesced [fo][j] stores.
__global__ __launch_bounds__(256) void k_xwt(const float* __restrict__ x,
                                             const float* __restrict__ dis,
                                             const u16* __restrict__ Wb,
                                             u16* __restrict__ xwT) {
  __shared__ __align__(16) u16 As[32 * 256];     // slot = r*32 + (c8^(r&7))
  __shared__ __align__(16) u16 LT[256 * 34];     // [fo][j], pad 34
  const int j0 = blockIdx.x * 32;
  const int t = threadIdx.x, lane = t & 63, w = t >> 6;
  const int wr = w >> 1, wc = w & 1;

  // stage A: bf16(dis[j] * x[j][f]), swizzled
#pragma unroll
  for (int q = 0; q < 4; ++q) {
    int chunk = t * 4 + q;           // 0..1023
    int r = chunk >> 5, c8 = chunk & 31;
    const float* g = x + (size_t)(j0 + r) * FF + c8 * 8;
    f32x4 v0 = *reinterpret_cast<const f32x4*>(g);
    f32x4 v1 = *reinterpret_cast<const f32x4*>(g + 4);
    float d = dis[j0 + r];
    s16x8 o;
#pragma unroll
    for (int e = 0; e < 4; ++e) o[e] = (short)f2bf_rne(v0[e] * d);
#pragma unroll
    for (int e = 0; e < 4; ++e) o[4 + e] = (short)f2bf_rne(v1[e] * d);
    *reinterpret_cast<s16x8*>(&As[(r * 32 + (c8 ^ (r & 7))) * 8]) = o;
  }
  __syncthreads();

  f32x4 occ[8] = {};
#pragma unroll
  for (int ks = 0; ks < 8; ++ks) {
    int cg = ks * 4 + (lane >> 4);
    int ar = wr * 16 + (lane & 15);
    bf16x8 af = __builtin_bit_cast(bf16x8,
        *reinterpret_cast<const s16x8*>(&As[(ar * 32 + (cg ^ (ar & 7))) * 8]));
#pragma unroll
    for (int ni = 0; ni < 8; ++ni) {
      int n = wc * 128 + ni * 16 + (lane & 15);
      bf16x8 bfv = __builtin_bit_cast(bf16x8,
          *reinterpret_cast<const s16x8*>(Wb + (size_t)n * FF + cg * 8));
      occ[ni] = __builtin_amdgcn_mfma_f32_16x16x32_bf16(af, bfv, occ[ni], 0, 0, 0);
    }
  }

  // transpose through LDS
  int rj0 = wr * 16 + (lane >> 4) * 4;
#pragma unroll
  for (int ni = 0; ni < 8; ++ni) {
    int c = wc * 128 + ni * 16 + (lane & 15);
#pragma unroll
    for (int e = 0; e < 4; ++e)
      LT[c * 34 + rj0 + e] = f2bf_rne(occ[ni][e]);
  }
  __syncthreads();

  // thread t = fo: 32 contiguous j -> 4x16B stores
  const unsigned* lp = reinterpret_cast<const unsigned*>(&LT[t * 34]);
  unsigned vals[16];
#pragma unroll
  for (int k = 0; k < 16; ++k) vals[k] = lp[k];
  u16* dst = xwT + (size_t)t * NN + j0;
#pragma unroll
  for (int q = 0; q < 4; ++q) {
    u32x4 vv;
#pragma unroll
    for (int e = 0; e < 4; ++e) vv[e] = vals[q * 4 + e];
    *reinterpret_cast<u32x4*>(dst + q * 8) = vv;
  }
}

// -------- K4: split-K GEMM  part[kc](i, fo) = adjb_tile @ xwT^T --------
// BM=BN=128 BK=64, kc=4, bn=2, grid 512 (2 blocks/CU), 256 thr = 4 waves
// (2x2, wave-tile 64x64). 2-buf double-buffer, __syncthreads schedule
// (compiler-managed waitcnt -- R3's raw-barrier schedule reverted).
// XCD decode: xcd=wg&7 -> (bn,kc) so each XCD's 64 blocks share one 512KB
// B-slice (L2-resident). A = adjb bf16 via global_load_lds (L3-hot).
__global__ __launch_bounds__(256, 2) void k_gemm1(const u16* __restrict__ adjb,
                                                  const u16* __restrict__ xwT,
                                                  float* __restrict__ part) {
  __shared__ __align__(16) u16 As[2][128 * 64];   // 32 KB
  __shared__ __align__(16) u16 Bs[2][128 * 64];   // 32 KB
  const int wg = blockIdx.x;
  const int xcd = wg & 7;
  const int bn = xcd & 1, kc = xcd >> 1;
  const int bm = wg >> 3;               // 0..63
  const size_t i0 = (size_t)bm * 128;
  const int k0 = kc * 2048;
  const int fo0 = bn * 128;
  const int t = threadIdx.x;
  const int lane = t & 63;
  const int w = t >> 6;                 // 0..3
  const int wr = w >> 1, wc = w & 1;    // 2x2 waves of 64x64

  f32x4 acc[4][4] = {};

  auto STAGE = [&](int buf, int kt) {
    const int kbase = k0 + kt * 64;
#pragma unroll
    for (int q = 0; q < 4; ++q) {
      int s = (w * 4 + q) * 64 + lane;
      int r = s >> 3, cg = (s & 7) ^ (r & 7);
      gld_lds16(adjb + (i0 + r) * (size_t)NN + kbase + cg * 8,
                &As[buf][(w * 4 + q) * 512]);
    }
#pragma unroll
    for (int q = 0; q < 4; ++q) {
      int s = (w * 4 + q) * 64 + lane;
      int r = s >> 3, cg = (s & 7) ^ (r & 7);
      gld_lds16(xwT + (size_t)(fo0 + r) * NN + kbase + cg * 8,
                &Bs[buf][(w * 4 + q) * 512]);
    }
  };
  auto COMPUTE = [&](int buf) {
#pragma unroll
    for (int kk = 0; kk < 2; ++kk) {
      const int cg = kk * 4 + (lane >> 4);
      bf16x8 af[4], bfv[4];
#pragma unroll
      for (int mi = 0; mi < 4; ++mi) {
        int r = wr * 64 + mi * 16 + (lane & 15);
        af[mi] = __builtin_bit_cast(bf16x8,
            *reinterpret_cast<const s16x8*>(&As[buf][(r * 8 + (cg ^ (r & 7))) * 8]));
      }
#pragma unroll
      for (int ni = 0; ni < 4; ++ni) {
        int n = wc * 64 + ni * 16 + (lane & 15);
        bfv[ni] = __builtin_bit_cast(bf16x8,
            *reinterpret_cast<const s16x8*>(&Bs[buf][(n * 8 + (cg ^ (n & 7))) * 8]));
      }
#pragma unroll
      for (int mi = 0; mi < 4; ++mi)
#pragma unroll
        for (int ni = 0; ni < 4; ++ni)
          acc[mi][ni] = __builtin_amdgcn_mfma_f32_16x16x32_bf16(af[mi], bfv[ni], acc[mi][ni], 0, 0, 0);
    }
  };

  STAGE(0, 0);
  __syncthreads();
  for (int kt = 0; kt < 32; ++kt) {
    int buf = kt & 1;
    if (kt < 31) STAGE(buf ^ 1, kt + 1);
    COMPUTE(buf);
    __syncthreads();
  }

  float* pout = part + (size_t)kc * ((size_t)NN * FF);
#pragma unroll
  for (int mi = 0; mi < 4; ++mi) {
    int rbase = wr * 64 + mi * 16 + ((lane >> 4) * 4);
#pragma unroll
    for (int ni = 0; ni < 4; ++ni) {
      int cc = fo0 + wc * 64 + ni * 16 + (lane & 15);
#pragma unroll
      for (int e = 0; e < 4; ++e)
        pout[(i0 + rbase + e) * FF + cc] = acc[mi][ni][e];
    }
  }
}

// -------- K5: out = dis[i] * sum_kc part + bias  (pure streaming) --------
__global__ __launch_bounds__(256) void k_out_lite(const float* __restrict__ part,
                                                  const float* __restrict__ dis,
                                                  const float* __restrict__ bias,
                                                  float* __restrict__ out) {
  size_t idx = ((size_t)blockIdx.x * 256 + threadIdx.x) * 4;
  int i = (int)(idx >> 8);
  int c = (int)(idx & 255);
  const size_t SL = (size_t)NN * FF;
  f32x4 s = *reinterpret_cast<const f32x4*>(part + idx)
          + *reinterpret_cast<const f32x4*>(part + SL + idx)
          + *reinterpret_cast<const f32x4*>(part + 2 * SL + idx)
          + *reinterpret_cast<const f32x4*>(part + 3 * SL + idx);
  float d = dis[i];
  f32x4 bb = *reinterpret_cast<const f32x4*>(bias + c);
  f32x4 o = s * d + bb;
  *reinterpret_cast<f32x4*>(out + idx) = o;
}

extern "C" void kernel_launch(void* const* d_in, const int* in_sizes, int n_in,
                              void* d_out, int out_size, void* d_ws, size_t ws_size,
                              hipStream_t stream) {
  (void)in_sizes; (void)n_in; (void)out_size; (void)ws_size;
  const float* x   = (const float*)d_in[0];
  const float* adj = (const float*)d_in[1];
  const float* W   = (const float*)d_in[2];
  const float* b   = (const float*)d_in[3];
  float* out = (float*)d_out;
  char* ws = (char*)d_ws;

  // ws: dis 32KB @0 | xwT 4MB @64KB | Wb 128KB @(64KB+4MB) | part 32MB @8MB | adjb 128MB @48MB
  float* dis  = (float*)ws;
  u16*   xwT  = (u16*)(ws + (64u << 10));
  u16*   Wb   = (u16*)(ws + (64u << 10) + (4u << 20));
  float* part = (float*)(ws + (8u << 20));
  u16*   adjb = (u16*)(ws + (48u << 20));

  k_rowsum_cvt<<<dim3(8192), dim3(256), 0, stream>>>(adj, adjb, dis);
  k_wb<<<dim3(64), dim3(256), 0, stream>>>(W, Wb);
  k_xwt<<<dim3(256), dim3(256), 0, stream>>>(x, dis, Wb, xwT);
  k_gemm1<<<dim3(512), dim3(256), 0, stream>>>(adjb, xwT, part);
  k_out_lite<<<dim3(2048), dim3(256), 0, stream>>>(part, dis, b, out);
}